// Round 4
// baseline (206.934 us; speedup 1.0000x reference)
//
#include <hip/hip_runtime.h>
#include <hip/hip_bf16.h>

// FractalTransformer fused kernels, round 4.
// vs r3: M_wave=64 (afrag[4][8], 128 VGPR) -> 4 MFMAs per ds_read_b128,
// halving the streamed-LDS wall (the measured serial floor). One WG covers
// all 256 e (grid 1024, 2 exact co-residency rounds at 2 WGs/CU). v back to
// bf16 (register economy; precision proven in r1/r2). Zero-C MFMA peel.
// launch_bounds(256,8) pins VGPR <=256 (8 waves/CU class).

typedef __attribute__((ext_vector_type(8))) short short8;
typedef __attribute__((ext_vector_type(4))) float f32x4;
typedef __attribute__((ext_vector_type(4))) unsigned short ushort4v;

#define DD 256
#define SS 512
#define KVB 32
#define LOG2E 1.4426950408889634f
#define LN2   0.6931471805599453f

__device__ __forceinline__ unsigned short f2bf(float f) {
  unsigned int b = __float_as_uint(f);
  b += 0x7FFFu + ((b >> 16) & 1u);   // RNE
  return (unsigned short)(b >> 16);
}
__device__ __forceinline__ float bf2f(unsigned short u) {
  return __uint_as_float(((unsigned int)u) << 16);
}
__device__ __forceinline__ short8 cvt8(f32x4 lo, f32x4 hi) {
  short8 r;
  r[0]=(short)f2bf(lo[0]); r[1]=(short)f2bf(lo[1]);
  r[2]=(short)f2bf(lo[2]); r[3]=(short)f2bf(lo[3]);
  r[4]=(short)f2bf(hi[0]); r[5]=(short)f2bf(hi[1]);
  r[6]=(short)f2bf(hi[2]); r[7]=(short)f2bf(hi[3]);
  return r;
}
__device__ __forceinline__ void gload16(const void* g, void* l) {
  __builtin_amdgcn_global_load_lds(
      (const __attribute__((address_space(1))) void*)g,
      (__attribute__((address_space(3))) void*)l,
      16, 0, 0);
}

// ------------------------------------------------------------------
// One-time: bf16-convert 6 weights + (w_al + I). out = 7 x [256][256] bf16.
// ------------------------------------------------------------------
__global__ __launch_bounds__(256) void prep_weights(
    const float* __restrict__ w0, const float* __restrict__ w1,
    const float* __restrict__ w2, const float* __restrict__ w3,
    const float* __restrict__ w4, const float* __restrict__ w5,
    const float* __restrict__ wal, unsigned short* __restrict__ out)
{
  const int bi = blockIdx.x;               // 7*32
  const int m = bi >> 5;
  const int off = ((bi & 31) * 256 + threadIdx.x) * 8;
  const float* src = m==0?w0: m==1?w1: m==2?w2: m==3?w3: m==4?w4: m==5?w5: wal;
  f32x4 a = *(const f32x4*)(src + off);
  f32x4 b = *(const f32x4*)(src + off + 4);
  if (m == 6) {                            // fold residual: + I
    const int e = off >> 8, d = off & 255;
#pragma unroll
    for (int jj = 0; jj < 4; ++jj) {
      if (e == d + jj)     a[jj] += 1.0f;
      if (e == d + 4 + jj) b[jj] += 1.0f;
    }
  }
  *(short8*)(out + (size_t)m * 65536 + off) = cvt8(a, b);
}

// ------------------------------------------------------------------
// out[1024,256] = A @ Wbf^T (+res1)(+res2). grid 256 = 64 rowblk x 4 colblk.
// ------------------------------------------------------------------
__global__ __launch_bounds__(256) void linear_bf(
    const float* __restrict__ A, const unsigned short* __restrict__ Wbf,
    const float* __restrict__ res1, const float* __restrict__ res2,
    float* __restrict__ out)
{
  const int bi = blockIdx.x;
  const int rb = (bi >> 2) * 16;
  const int cb = (bi & 3) * 64;
  const int tid = threadIdx.x;
  const int wv = tid >> 6, lane = tid & 63;
  const int g = lane >> 4, c = lane & 15;
  const int arow = rb + c;
  const int wrow = cb + wv * 16 + c;

  f32x4 acc = (f32x4){0.f, 0.f, 0.f, 0.f};
#pragma unroll
  for (int ks = 0; ks < 8; ++ks) {
    const int d0 = ks * 32 + g * 8;
    f32x4 a0 = *(const f32x4*)(A + arow * DD + d0);
    f32x4 a1 = *(const f32x4*)(A + arow * DD + d0 + 4);
    short8 av = cvt8(a0, a1);
    short8 bv = *(const short8*)(Wbf + wrow * DD + d0);
    acc = __builtin_amdgcn_mfma_f32_16x16x32_bf16(av, bv, acc, 0, 0, 0);
  }
#pragma unroll
  for (int j = 0; j < 4; ++j) {
    const int ro = rb + g * 4 + j;
    const int co = cb + wv * 16 + c;
    float v = acc[j];
    if (res1) v += res1[ro * DD + co];
    if (res2) v += res2[ro * DD + co];
    out[ro * DD + co] = v;
  }
}

// ------------------------------------------------------------------
// q = (X + X@Wq^T)*log2e (f32);  k,v = bf16(X + X@{Wk,Wv}^T)
// ------------------------------------------------------------------
__global__ __launch_bounds__(256) void linear_qkv(
    const float* __restrict__ X,
    const unsigned short* __restrict__ Wq, const unsigned short* __restrict__ Wk,
    const unsigned short* __restrict__ Wv,
    float* __restrict__ qout, unsigned short* __restrict__ kout,
    unsigned short* __restrict__ vout)
{
  const int bi = blockIdx.x;
  const int rb = (bi >> 2) * 16;
  const int cb = (bi & 3) * 64;
  const int tid = threadIdx.x;
  const int wv = tid >> 6, lane = tid & 63;
  const int g = lane >> 4, c = lane & 15;
  const int arow = rb + c;
  const int wrow = cb + wv * 16 + c;

  f32x4 aq = (f32x4){0.f,0.f,0.f,0.f};
  f32x4 ak = (f32x4){0.f,0.f,0.f,0.f};
  f32x4 av_ = (f32x4){0.f,0.f,0.f,0.f};
#pragma unroll
  for (int ks = 0; ks < 8; ++ks) {
    const int d0 = ks * 32 + g * 8;
    f32x4 a0 = *(const f32x4*)(X + arow * DD + d0);
    f32x4 a1 = *(const f32x4*)(X + arow * DD + d0 + 4);
    short8 af = cvt8(a0, a1);
    short8 bq = *(const short8*)(Wq + wrow * DD + d0);
    aq = __builtin_amdgcn_mfma_f32_16x16x32_bf16(af, bq, aq, 0, 0, 0);
    short8 bk = *(const short8*)(Wk + wrow * DD + d0);
    ak = __builtin_amdgcn_mfma_f32_16x16x32_bf16(af, bk, ak, 0, 0, 0);
    short8 bv = *(const short8*)(Wv + wrow * DD + d0);
    av_ = __builtin_amdgcn_mfma_f32_16x16x32_bf16(af, bv, av_, 0, 0, 0);
  }
#pragma unroll
  for (int j = 0; j < 4; ++j) {
    const int ro = rb + g * 4 + j;
    const int co = cb + wv * 16 + c;
    const float base = X[ro * DD + co];
    qout[ro * DD + co] = (base + aq[j]) * LOG2E;
    kout[ro * DD + co] = f2bf(base + ak[j]);
    vout[ro * DD + co] = f2bf(base + av_[j]);
  }
}

// ------------------------------------------------------------------
// Fused fractal attention v4. Grid 1024 = b x sq. 4 waves x 64 lanes.
// Wave owns 64 e-rows (i in 0..3) -> 4 MFMAs per ds_read_b128.
// KVB=32, k double-buffered 2x16KB LDS; v bf16 direct from global/L2.
// ------------------------------------------------------------------
__global__ __launch_bounds__(256, 8) void fractal_attn(
    const unsigned short* __restrict__ walI,   // bf16 (wal+I), [256][256]
    const float* __restrict__ q,               // f32, pre-scaled by log2e
    const unsigned short* __restrict__ kbf,    // bf16 [b][s][d]
    const unsigned short* __restrict__ vbf,    // bf16 [b][s][d]
    float* __restrict__ vsum)
{
  __shared__ char smem[2][16384];   // k tiles only

  const int wg = blockIdx.x;        // 1024
  const int sq = wg & 511;
  const int b  = wg >> 9;
  const int tid = threadIdx.x;      // 256
  const int wv = tid >> 6, lane = tid & 63;
  const int g = lane >> 4, c = lane & 15;

  // ---- k staging: tile = 32 rows x 32 granules(16B); 4 granules/thread ----
  const unsigned short* kbase = kbf + (size_t)b * SS * DD;
  int srco[4];
#pragma unroll
  for (int it = 0; it < 4; ++it) {
    const int p = it * 256 + tid;            // granule 0..1023
    const int row = p >> 5, gc = p & 31;
    srco[it] = row * DD + (gc ^ (row & 7)) * 8;   // inverse-swizzled source
  }
  auto stage = [&](int t) {
    char* dst = (char*)smem[t & 1];
    const unsigned short* ks = kbase + t * KVB * DD;
#pragma unroll
    for (int it = 0; it < 4; ++it)
      gload16(ks + srco[it], dst + (it * 256 + tid) * 16);
  };

  stage(0);   // in flight while we build A'

  // ---- A' fragments: wave owns e in [wv*64, wv*64+64) ----
  short8 afrag[4][8];
  {
    const float* qrow = q + (size_t)(b * SS + sq) * DD;
#pragma unroll
    for (int i = 0; i < 4; ++i) {
      const int e = wv * 64 + i * 16 + c;
      const unsigned short* wrow = walI + (size_t)e * DD;
#pragma unroll
      for (int ks = 0; ks < 8; ++ks) {
        const int d0 = ks * 32 + g * 8;
        short8 w8 = *(const short8*)(wrow + d0);
        f32x4 q0 = *(const f32x4*)(qrow + d0);
        f32x4 q1 = *(const f32x4*)(qrow + d0 + 4);
        f32x4 lo, hi;
        lo[0] = bf2f((unsigned short)w8[0]) * q0[0];
        lo[1] = bf2f((unsigned short)w8[1]) * q0[1];
        lo[2] = bf2f((unsigned short)w8[2]) * q0[2];
        lo[3] = bf2f((unsigned short)w8[3]) * q0[3];
        hi[0] = bf2f((unsigned short)w8[4]) * q1[0];
        hi[1] = bf2f((unsigned short)w8[5]) * q1[1];
        hi[2] = bf2f((unsigned short)w8[6]) * q1[2];
        hi[3] = bf2f((unsigned short)w8[7]) * q1[3];
        afrag[i][ks] = cvt8(lo, hi);
      }
    }
  }

  // ---- k-read bases: addr(n,ks) = kbA(^64 if ks odd) + n*8192 + (ks>>1)*128
  const int kbA = c * 512 + ((g ^ (c & 3)) << 4) + (((c >> 2) & 1) << 6);
  const int kbB = kbA ^ 64;

  // ---- v (bf16) global offsets: row n*16+c, col e = wv*64 + i*16 + g*4 ----
  const unsigned short* vbase = vbf + (size_t)b * SS * DD;
  const int vofbase = c * DD + wv * 64 + g * 4;   // + n*16*DD + i*16

  // ---- state: 16 e-slots per lane (e = wv*64 + i*16 + g*4 + j) ----
  float mst[16], sst[16], vst[16];
#pragma unroll
  for (int s = 0; s < 16; ++s) { mst[s] = -1e30f; sst[s] = 0.f; vst[s] = 0.f; }

  const f32x4 zeroc = (f32x4){0.f, 0.f, 0.f, 0.f};

  for (int t = 0; t < 16; ++t) {
    __syncthreads();                 // buf[t&1] fully staged (vmcnt drain)

    // v loads (bf16, 8B each) for THIS tile; overlap with MFMA phase.
    const unsigned short* vt = vbase + (size_t)t * KVB * DD;
    ushort4v vq[2][4];
#pragma unroll
    for (int n = 0; n < 2; ++n)
#pragma unroll
      for (int i = 0; i < 4; ++i)
        vq[n][i] = *(const ushort4v*)(vt + vofbase + n * 16 * DD + i * 16);
    if (t < 15) stage(t + 1);        // prefetch next tile

    const char* kb = (const char*)smem[t & 1];
    f32x4 acc[4][2];

    // ---- ks=0/1 peel with C=0 ----
    {
      short8 bA0 = *(const short8*)(kb + kbA);
      short8 bA1 = *(const short8*)(kb + kbA + 8192);
#pragma unroll
      for (int i = 0; i < 4; ++i) {
        acc[i][0] = __builtin_amdgcn_mfma_f32_16x16x32_bf16(afrag[i][0], bA0, zeroc, 0, 0, 0);
        acc[i][1] = __builtin_amdgcn_mfma_f32_16x16x32_bf16(afrag[i][0], bA1, zeroc, 0, 0, 0);
      }
      short8 bB0 = *(const short8*)(kb + kbB);
      short8 bB1 = *(const short8*)(kb + kbB + 8192);
#pragma unroll
      for (int i = 0; i < 4; ++i) {
        acc[i][0] = __builtin_amdgcn_mfma_f32_16x16x32_bf16(afrag[i][1], bB0, acc[i][0], 0, 0, 0);
        acc[i][1] = __builtin_amdgcn_mfma_f32_16x16x32_bf16(afrag[i][1], bB1, acc[i][1], 0, 0, 0);
      }
    }
#pragma unroll
    for (int ks2 = 1; ks2 < 4; ++ks2) {
      short8 bA0 = *(const short8*)(kb + kbA + ks2 * 128);
      short8 bA1 = *(const short8*)(kb + kbA + ks2 * 128 + 8192);
#pragma unroll
      for (int i = 0; i < 4; ++i) {
        acc[i][0] = __builtin_amdgcn_mfma_f32_16x16x32_bf16(afrag[i][2*ks2], bA0, acc[i][0], 0, 0, 0);
        acc[i][1] = __builtin_amdgcn_mfma_f32_16x16x32_bf16(afrag[i][2*ks2], bA1, acc[i][1], 0, 0, 0);
      }
      short8 bB0 = *(const short8*)(kb + kbB + ks2 * 128);
      short8 bB1 = *(const short8*)(kb + kbB + ks2 * 128 + 8192);
#pragma unroll
      for (int i = 0; i < 4; ++i) {
        acc[i][0] = __builtin_amdgcn_mfma_f32_16x16x32_bf16(afrag[i][2*ks2+1], bB0, acc[i][0], 0, 0, 0);
        acc[i][1] = __builtin_amdgcn_mfma_f32_16x16x32_bf16(afrag[i][2*ks2+1], bB1, acc[i][1], 0, 0, 0);
      }
    }

    // ---- online update: slot s = i*4+j; sk = t*32 + n*16 + c ----
#pragma unroll
    for (int n = 0; n < 2; ++n) {
#pragma unroll
      for (int i = 0; i < 4; ++i) {
#pragma unroll
        for (int j = 0; j < 4; ++j) {
          const int s = i * 4 + j;
          const float L = acc[i][n][j];
          mst[s] = fmaxf(mst[s], L);
          const float p = L * __builtin_amdgcn_exp2f(L);
          sst[s] += fabsf(p);
          vst[s] = fmaf(bf2f((unsigned short)vq[n][i][j]), p, vst[s]);
        }
      }
    }
  }

  // ---- merge across the 16 sk-lanes (same g => same e) ----
#pragma unroll
  for (int mask = 1; mask <= 8; mask <<= 1) {
#pragma unroll
    for (int s = 0; s < 16; ++s) {
      mst[s] = fmaxf(mst[s], __shfl_xor(mst[s], mask));
      sst[s] += __shfl_xor(sst[s], mask);
      vst[s] += __shfl_xor(vst[s], mask);
    }
  }

  if (c == 0) {
    float* orow = vsum + (size_t)(b * SS + sq) * DD;
#pragma unroll
    for (int i = 0; i < 4; ++i) {
      f32x4 o;
#pragma unroll
      for (int j = 0; j < 4; ++j) {
        const int s = i * 4 + j;
        const float tt = LN2 * __builtin_amdgcn_exp2f(-mst[s]);
        o[j] = vst[s] * tt / (sst[s] * tt + 1.0f);
      }
      *(f32x4*)(orow + wv * 64 + i * 16 + g * 4) = o;
    }
  }
}

// ------------------------------------------------------------------
extern "C" void kernel_launch(void* const* d_in, const int* in_sizes, int n_in,
                              void* d_out, int out_size, void* d_ws, size_t ws_size,
                              hipStream_t stream) {
  const float* x     = (const float*)d_in[0];
  const float* w_pre = (const float*)d_in[1];
  const float* w_q   = (const float*)d_in[2];
  const float* w_k   = (const float*)d_in[3];
  const float* w_va  = (const float*)d_in[4];
  const float* w_al  = (const float*)d_in[5];
  const float* w_vo  = (const float*)d_in[6];
  const float* w_end = (const float*)d_in[7];
  float* out = (float*)d_out;

  char* ws = (char*)d_ws;
  float* X    = (float*)(ws);
  float* q    = (float*)(ws + (1 << 20));
  float* vsum = (float*)(ws + (2 << 20));
  float* Y    = (float*)(ws + (3 << 20));
  unsigned short* k_bf = (unsigned short*)(ws + (4 << 20));          // 512KB
  unsigned short* v_bf = (unsigned short*)(ws + (4 << 20) + (512 << 10));
  unsigned short* wbf  = (unsigned short*)(ws + (5 << 20));
  // wbf order: pre, q, k, va, vo, end, walI(+I)

  prep_weights<<<224, 256, 0, stream>>>(w_pre, w_q, w_k, w_va, w_vo, w_end,
                                        w_al, wbf);
  linear_bf<<<256, 256, 0, stream>>>(x, wbf + 0 * 65536, nullptr, nullptr, X);
  linear_qkv<<<256, 256, 0, stream>>>(X, wbf + 1 * 65536, wbf + 2 * 65536,
                                      wbf + 3 * 65536, q, k_bf, v_bf);
  fractal_attn<<<1024, 256, 0, stream>>>(wbf + 6 * 65536, q, k_bf, v_bf, vsum);
  linear_bf<<<256, 256, 0, stream>>>(vsum, wbf + 4 * 65536, vsum, X, Y);
  linear_bf<<<256, 256, 0, stream>>>(Y, wbf + 5 * 65536, nullptr, nullptr, out);
}

// Round 6
// 120.931 us; speedup vs baseline: 1.7112x; 1.7112x over previous
//
#include <hip/hip_runtime.h>
#include <hip/hip_bf16.h>

// FractalTransformer fused kernels, round 6 (= r5 + pack_kv grid fix).
// r5 bug: pack_kv launched 65536 threads but needs 32768 (k) + 65536 (v)
// = 98304 -> v-fragments for b=1 never written (absmax 0.455 over batch 1).
// Architecture unchanged: M_wave=64, no LDS/no barriers, k/v pre-packed in
// MFMA-fragment order in global (L2-resident coalesced streams), f16 MFMA,
// 1-wave blocks grid 4096, launch_bounds(64,2).

typedef __attribute__((ext_vector_type(8))) short short8;
typedef __attribute__((ext_vector_type(4))) float f32x4;
typedef __attribute__((ext_vector_type(8))) _Float16 half8;
typedef __attribute__((ext_vector_type(4))) _Float16 half4;

#define DD 256
#define SS 512
#define LOG2E 1.4426950408889634f
#define LN2   0.6931471805599453f

__device__ __forceinline__ unsigned short f2bf(float f) {
  unsigned int b = __float_as_uint(f);
  b += 0x7FFFu + ((b >> 16) & 1u);   // RNE
  return (unsigned short)(b >> 16);
}
__device__ __forceinline__ short8 cvt8(f32x4 lo, f32x4 hi) {
  short8 r;
  r[0]=(short)f2bf(lo[0]); r[1]=(short)f2bf(lo[1]);
  r[2]=(short)f2bf(lo[2]); r[3]=(short)f2bf(lo[3]);
  r[4]=(short)f2bf(hi[0]); r[5]=(short)f2bf(hi[1]);
  r[6]=(short)f2bf(hi[2]); r[7]=(short)f2bf(hi[3]);
  return r;
}

// ------------------------------------------------------------------
// One-time: bf16-convert 6 weights; (w_al + I) -> f16. out = 7 x [256][256].
// ------------------------------------------------------------------
__global__ __launch_bounds__(256) void prep_weights(
    const float* __restrict__ w0, const float* __restrict__ w1,
    const float* __restrict__ w2, const float* __restrict__ w3,
    const float* __restrict__ w4, const float* __restrict__ w5,
    const float* __restrict__ wal, unsigned short* __restrict__ out)
{
  const int bi = blockIdx.x;               // 7*32
  const int m = bi >> 5;
  const int off = ((bi & 31) * 256 + threadIdx.x) * 8;
  const float* src = m==0?w0: m==1?w1: m==2?w2: m==3?w3: m==4?w4: m==5?w5: wal;
  f32x4 a = *(const f32x4*)(src + off);
  f32x4 b = *(const f32x4*)(src + off + 4);
  if (m == 6) {                            // fold residual (+I), store f16
    const int e = off >> 8, d = off & 255;
#pragma unroll
    for (int jj = 0; jj < 4; ++jj) {
      if (e == d + jj)     a[jj] += 1.0f;
      if (e == d + 4 + jj) b[jj] += 1.0f;
    }
    half8 h;
#pragma unroll
    for (int jj = 0; jj < 4; ++jj) {
      h[jj]     = (_Float16)a[jj];
      h[jj + 4] = (_Float16)b[jj];
    }
    *(half8*)(out + (size_t)m * 65536 + off) = h;
  } else {
    *(short8*)(out + (size_t)m * 65536 + off) = cvt8(a, b);
  }
}

// ------------------------------------------------------------------
// out[1024,256] = A @ Wbf^T (+res1)(+res2). grid 256 = 64 rowblk x 4 colblk.
// ------------------------------------------------------------------
__global__ __launch_bounds__(256) void linear_bf(
    const float* __restrict__ A, const unsigned short* __restrict__ Wbf,
    const float* __restrict__ res1, const float* __restrict__ res2,
    float* __restrict__ out)
{
  const int bi = blockIdx.x;
  const int rb = (bi >> 2) * 16;
  const int cb = (bi & 3) * 64;
  const int tid = threadIdx.x;
  const int wv = tid >> 6, lane = tid & 63;
  const int g = lane >> 4, c = lane & 15;
  const int arow = rb + c;
  const int wrow = cb + wv * 16 + c;

  f32x4 acc = (f32x4){0.f, 0.f, 0.f, 0.f};
#pragma unroll
  for (int ks = 0; ks < 8; ++ks) {
    const int d0 = ks * 32 + g * 8;
    f32x4 a0 = *(const f32x4*)(A + arow * DD + d0);
    f32x4 a1 = *(const f32x4*)(A + arow * DD + d0 + 4);
    short8 av = cvt8(a0, a1);
    short8 bv = *(const short8*)(Wbf + wrow * DD + d0);
    acc = __builtin_amdgcn_mfma_f32_16x16x32_bf16(av, bv, acc, 0, 0, 0);
  }
#pragma unroll
  for (int j = 0; j < 4; ++j) {
    const int ro = rb + g * 4 + j;
    const int co = cb + wv * 16 + c;
    float v = acc[j];
    if (res1) v += res1[ro * DD + co];
    if (res2) v += res2[ro * DD + co];
    out[ro * DD + co] = v;
  }
}

// ------------------------------------------------------------------
// q = f16((X + X@Wq^T)*log2e);  k,v = f16(X + X@{Wk,Wv}^T)
// ------------------------------------------------------------------
__global__ __launch_bounds__(256) void linear_qkv(
    const float* __restrict__ X,
    const unsigned short* __restrict__ Wq, const unsigned short* __restrict__ Wk,
    const unsigned short* __restrict__ Wv,
    _Float16* __restrict__ qout, _Float16* __restrict__ kout,
    _Float16* __restrict__ vout)
{
  const int bi = blockIdx.x;
  const int rb = (bi >> 2) * 16;
  const int cb = (bi & 3) * 64;
  const int tid = threadIdx.x;
  const int wv = tid >> 6, lane = tid & 63;
  const int g = lane >> 4, c = lane & 15;
  const int arow = rb + c;
  const int wrow = cb + wv * 16 + c;

  f32x4 aq = (f32x4){0.f,0.f,0.f,0.f};
  f32x4 ak = (f32x4){0.f,0.f,0.f,0.f};
  f32x4 av_ = (f32x4){0.f,0.f,0.f,0.f};
#pragma unroll
  for (int ks = 0; ks < 8; ++ks) {
    const int d0 = ks * 32 + g * 8;
    f32x4 a0 = *(const f32x4*)(X + arow * DD + d0);
    f32x4 a1 = *(const f32x4*)(X + arow * DD + d0 + 4);
    short8 af = cvt8(a0, a1);
    short8 bq = *(const short8*)(Wq + wrow * DD + d0);
    aq = __builtin_amdgcn_mfma_f32_16x16x32_bf16(af, bq, aq, 0, 0, 0);
    short8 bk = *(const short8*)(Wk + wrow * DD + d0);
    ak = __builtin_amdgcn_mfma_f32_16x16x32_bf16(af, bk, ak, 0, 0, 0);
    short8 bv = *(const short8*)(Wv + wrow * DD + d0);
    av_ = __builtin_amdgcn_mfma_f32_16x16x32_bf16(af, bv, av_, 0, 0, 0);
  }
#pragma unroll
  for (int j = 0; j < 4; ++j) {
    const int ro = rb + g * 4 + j;
    const int co = cb + wv * 16 + c;
    const float base = X[ro * DD + co];
    qout[ro * DD + co] = (_Float16)((base + aq[j]) * LOG2E);
    kout[ro * DD + co] = (_Float16)(base + ak[j]);
    vout[ro * DD + co] = (_Float16)(base + av_[j]);
  }
}

// ------------------------------------------------------------------
// Pack k,v (f16, [b][s][d]) into MFMA-fragment order.
// k: ids [0, 32768): chunk id = b*16384 + t2*512 + ks*64 + lane -> 8 f16:
//   k[b][t2*16 + (lane&15)][ks*32 + (lane>>4)*8 + 0..7]
// v: ids [32768, 98304): id2 = b*32768 + t2*1024 + wv*256 + i*64 + lane
//   -> 4 f16: v[b][t2*16 + (lane&15)][wv*64 + i*16 + (lane>>4)*4 + 0..3]
// ------------------------------------------------------------------
__global__ __launch_bounds__(256) void pack_kv(
    const _Float16* __restrict__ k, const _Float16* __restrict__ v,
    _Float16* __restrict__ kfrag, _Float16* __restrict__ vfrag)
{
  const int id = blockIdx.x * 256 + threadIdx.x;   // 98304
  if (id < 32768) {
    const int lane = id & 63, ks = (id >> 6) & 7, t2 = (id >> 9) & 31, b = id >> 14;
    const int g = lane >> 4, c = lane & 15;
    const _Float16* src = k + ((size_t)(b * SS + t2 * 16 + c) * DD + ks * 32 + g * 8);
    *(half8*)(kfrag + (size_t)id * 8) = *(const half8*)src;
  } else {
    const int id2 = id - 32768;                    // 0..65535
    const int lane = id2 & 63, i = (id2 >> 6) & 3, wv = (id2 >> 8) & 3,
              t2 = (id2 >> 10) & 31, b = id2 >> 15;
    const int g = lane >> 4, c = lane & 15;
    const _Float16* src = v + ((size_t)(b * SS + t2 * 16 + c) * DD + wv * 64 + i * 16 + g * 4);
    *(half4*)(vfrag + (size_t)id2 * 4) = *(const half4*)src;
  }
}

// ------------------------------------------------------------------
// Fused fractal attention v5. Grid 4096 = b x sq x wv; 1 wave per block.
// Wave owns 64 e-rows (i=0..3). No LDS, no barriers: k/v read from
// fragment-packed global (coalesced 1KB/8B wave loads, L2-resident).
// ------------------------------------------------------------------
__global__ __launch_bounds__(64, 2) void fractal_attn(
    const _Float16* __restrict__ walI,   // f16 (wal+I), [256][256]
    const _Float16* __restrict__ qf,     // f16, pre-scaled by log2e
    const _Float16* __restrict__ kfrag,
    const _Float16* __restrict__ vfrag,
    float* __restrict__ vsum)
{
  const int bid = blockIdx.x;            // 4096
  const int wv = bid & 3;
  const int sq = (bid >> 2) & 511;
  const int b  = bid >> 11;
  const int lane = threadIdx.x;          // 64
  const int g = lane >> 4, c = lane & 15;

  // ---- A' fragments: wave owns e in [wv*64, wv*64+64) ----
  half8 afrag[4][8];
  {
    const _Float16* qrow = qf + (size_t)(b * SS + sq) * DD;
    half8 q8[8];
#pragma unroll
    for (int ks = 0; ks < 8; ++ks)
      q8[ks] = *(const half8*)(qrow + ks * 32 + g * 8);
#pragma unroll
    for (int i = 0; i < 4; ++i) {
      const int e = wv * 64 + i * 16 + c;
      const _Float16* wrow = walI + (size_t)e * DD;
#pragma unroll
      for (int ks = 0; ks < 8; ++ks)
        afrag[i][ks] = (*(const half8*)(wrow + ks * 32 + g * 8)) * q8[ks];
    }
  }

  // ---- fragment stream bases ----
  const _Float16* kfb = kfrag + (size_t)b * 131072 + lane * 8;   // + t2*4096 + ks*512
  const _Float16* vfb = vfrag + (size_t)b * 131072 + wv * 1024 + lane * 4;  // + t2*4096 + i*256

  // ---- state: 16 e-slots per lane (e = wv*64 + i*16 + g*4 + j) ----
  float mst[16], sst[16], vst[16];
#pragma unroll
  for (int s = 0; s < 16; ++s) { mst[s] = -1e30f; sst[s] = 0.f; vst[s] = 0.f; }

  for (int t2 = 0; t2 < 32; ++t2) {
    const _Float16* kf = kfb + t2 * 4096;
    const _Float16* vf = vfb + t2 * 4096;

    half8 bf[8];
#pragma unroll
    for (int ks = 0; ks < 8; ++ks)
      bf[ks] = *(const half8*)(kf + ks * 512);
    half4 vvq[4];
#pragma unroll
    for (int i = 0; i < 4; ++i)
      vvq[i] = *(const half4*)(vf + i * 256);

    f32x4 acc[4];
    __builtin_amdgcn_s_setprio(1);
    {
      const f32x4 zeroc = (f32x4){0.f, 0.f, 0.f, 0.f};
#pragma unroll
      for (int i = 0; i < 4; ++i)
        acc[i] = __builtin_amdgcn_mfma_f32_16x16x32_f16(afrag[i][0], bf[0], zeroc, 0, 0, 0);
#pragma unroll
      for (int ks = 1; ks < 8; ++ks)
#pragma unroll
        for (int i = 0; i < 4; ++i)
          acc[i] = __builtin_amdgcn_mfma_f32_16x16x32_f16(afrag[i][ks], bf[ks], acc[i], 0, 0, 0);
    }
    __builtin_amdgcn_s_setprio(0);

    // ---- online update: slot s = i*4+j; sk = t2*16 + c ----
#pragma unroll
    for (int i = 0; i < 4; ++i) {
#pragma unroll
      for (int j = 0; j < 4; ++j) {
        const int s = i * 4 + j;
        const float L = acc[i][j];
        mst[s] = fmaxf(mst[s], L);
        const float p = L * __builtin_amdgcn_exp2f(L);
        sst[s] += fabsf(p);
        vst[s] = fmaf((float)vvq[i][j], p, vst[s]);
      }
    }
  }

  // ---- merge across the 16 sk-lanes (same g => same e) ----
#pragma unroll
  for (int mask = 1; mask <= 8; mask <<= 1) {
#pragma unroll
    for (int s = 0; s < 16; ++s) {
      mst[s] = fmaxf(mst[s], __shfl_xor(mst[s], mask));
      sst[s] += __shfl_xor(sst[s], mask);
      vst[s] += __shfl_xor(vst[s], mask);
    }
  }

  if (c == 0) {
    float* orow = vsum + (size_t)(b * SS + sq) * DD;
#pragma unroll
    for (int i = 0; i < 4; ++i) {
      f32x4 o;
#pragma unroll
      for (int j = 0; j < 4; ++j) {
        const int s = i * 4 + j;
        const float tt = LN2 * __builtin_amdgcn_exp2f(-mst[s]);
        o[j] = vst[s] * tt / (sst[s] * tt + 1.0f);
      }
      *(f32x4*)(orow + wv * 64 + i * 16 + g * 4) = o;
    }
  }
}

// ------------------------------------------------------------------
extern "C" void kernel_launch(void* const* d_in, const int* in_sizes, int n_in,
                              void* d_out, int out_size, void* d_ws, size_t ws_size,
                              hipStream_t stream) {
  const float* x     = (const float*)d_in[0];
  const float* w_pre = (const float*)d_in[1];
  const float* w_q   = (const float*)d_in[2];
  const float* w_k   = (const float*)d_in[3];
  const float* w_va  = (const float*)d_in[4];
  const float* w_al  = (const float*)d_in[5];
  const float* w_vo  = (const float*)d_in[6];
  const float* w_end = (const float*)d_in[7];
  float* out = (float*)d_out;

  char* ws = (char*)d_ws;
  float*    X     = (float*)(ws);                         // 1MB
  float*    Y     = (float*)(ws + (1 << 20));             // 1MB
  float*    vsum  = (float*)(ws + (2 << 20));             // 1MB
  _Float16* qf16  = (_Float16*)(ws + (3 << 20));          // 512KB
  _Float16* kf16  = (_Float16*)(ws + (3 << 20) + (512 << 10));
  _Float16* vf16  = (_Float16*)(ws + (4 << 20));
  _Float16* kfrag = (_Float16*)(ws + (4 << 20) + (512 << 10));  // 512KB
  _Float16* vfrag = (_Float16*)(ws + (5 << 20));                // 512KB
  unsigned short* wbf = (unsigned short*)(ws + (5 << 20) + (512 << 10));
  // wbf order: pre, q, k, va, vo, end, walI(+I, f16)

  prep_weights<<<224, 256, 0, stream>>>(w_pre, w_q, w_k, w_va, w_vo, w_end,
                                        w_al, wbf);
  linear_bf<<<256, 256, 0, stream>>>(x, wbf + 0 * 65536, nullptr, nullptr, X);
  linear_qkv<<<256, 256, 0, stream>>>(X, wbf + 1 * 65536, wbf + 2 * 65536,
                                      wbf + 3 * 65536, qf16, kf16, vf16);
  pack_kv<<<384, 256, 0, stream>>>(kf16, vf16, kfrag, vfrag);
  fractal_attn<<<4096, 64, 0, stream>>>((const _Float16*)(wbf + 6 * 65536),
                                        qf16, kfrag, vfrag, vsum);
  linear_bf<<<256, 256, 0, stream>>>(vsum, wbf + 4 * 65536, vsum, X, Y);
  linear_bf<<<256, 256, 0, stream>>>(Y, wbf + 5 * 65536, nullptr, nullptr, out);
}